// Round 7
// baseline (156.992 us; speedup 1.0000x reference)
//
#include <hip/hip_runtime.h>
#include <math.h>
#include <stdint.h>

#define BB 4
#define LL 2048
#define DD 512
#define KDIM 64
#define HH 8

typedef _Float16 f16;
typedef f16 f16x8 __attribute__((ext_vector_type(8)));
typedef f16 f16x4v __attribute__((ext_vector_type(4)));
typedef float f32x4 __attribute__((ext_vector_type(4)));

// Involutive XOR swizzle for 128B-row (attn) and 64B-row (GEMM) LDS tiles.
__device__ __forceinline__ int swz(int x) { return x ^ (((x >> 7) & 7) << 4); }

__device__ __forceinline__ void gload16(const void* g, void* l) {
    __builtin_amdgcn_global_load_lds(
        (const __attribute__((address_space(1))) void*)g,
        (__attribute__((address_space(3))) void*)l, 16, 0, 0);
}

// Counted-drain barrier (GEMM pipeline): wait own staging loads, raw barrier.
__device__ __forceinline__ void wait_barrier() {
    asm volatile("s_waitcnt vmcnt(0)" ::: "memory");
    __builtin_amdgcn_s_barrier();
}

// ---------------------------------------------------------------------------
// Prologue: weight dequant+transpose (4 weights) AND fp32->fp16 casts (3
// activations) in ONE launch. 1D grid: bid<1024 -> prep, else cast.
// WO (zi==3): k-index permuted k' = (k&7)*64 + (k>>3) so the final GEMM can
// read the attention output in per-head [b][h][q][64] layout.
// ---------------------------------------------------------------------------
__global__ __launch_bounds__(256)
void prologue(const int* __restrict__ w0, const int* __restrict__ w1,
              const int* __restrict__ w2, const int* __restrict__ w3,
              const float* s0, const float* s1, const float* s2, const float* s3,
              const float* z0, const float* z1, const float* z2, const float* z3,
              f16* o0, f16* o1, f16* o2, f16* o3,
              const float* __restrict__ xq, const float* __restrict__ xk,
              const float* __restrict__ xv, f16* cq, f16* ck, f16* cv)
{
    __shared__ float t[32][33];
    const int bid = blockIdx.x;
    if (bid < 1024) {
        const int zi = bid >> 8, rem = bid & 255;
        const int* W = zi == 0 ? w0 : zi == 1 ? w1 : zi == 2 ? w2 : w3;
        const float sc = *(zi == 0 ? s0 : zi == 1 ? s1 : zi == 2 ? s2 : s3);
        const float zp = *(zi == 0 ? z0 : zi == 1 ? z1 : zi == 2 ? z2 : z3);
        f16* WT = zi == 0 ? o0 : zi == 1 ? o1 : zi == 2 ? o2 : o3;
        const int n0 = (rem & 15) * 32, k0 = (rem >> 4) * 32;
        const int x = threadIdx.x & 31, y = threadIdx.x >> 5;  // 32 x 8
        #pragma unroll
        for (int i = 0; i < 32; i += 8)
            t[y + i][x] = ((float)W[(size_t)(k0 + y + i) * DD + n0 + x] - zp) * sc;
        __syncthreads();
        if (zi == 3) {
            const int k = k0 + x;
            const int kp = (k & 7) * 64 + (k >> 3);
            #pragma unroll
            for (int i = 0; i < 32; i += 8)
                WT[(size_t)(n0 + y + i) * DD + kp] = (f16)t[x][y + i];
        } else {
            #pragma unroll
            for (int i = 0; i < 32; i += 8)
                WT[(size_t)(n0 + y + i) * DD + k0 + x] = (f16)t[x][y + i];
        }
    } else {
        const int c = bid - 1024;
        const int yi = c >> 12, xb = c & 4095;
        const float* in = yi == 0 ? xq : yi == 1 ? xk : xv;
        f16* out = yi == 0 ? cq : yi == 1 ? ck : cv;
        const int i = (xb * 256 + threadIdx.x) * 4;
        float4 v = *(const float4*)(in + i);
        f16x4v o = {(f16)v.x, (f16)v.y, (f16)v.z, (f16)v.w};
        *(f16x4v*)(out + i) = o;
    }
}

// ---------------------------------------------------------------------------
// MFMA GEMM body: Out[M=8192][N=512] = A[M][512] @ WT^T + bias.
// 128x128 tile, BK=32, 4 waves (2x2), 4x4 16x16x32 frags per wave.
// Double-buffered LDS, counted-vmcnt pipeline (one barrier per K-step).
// EPI=0: f16 per-head row-major [b*H+h][L][64]     (Q, K)
// EPI=1: fp32 [M][N]; A is per-head [b][h][q][64] with permuted-k weights
// EPI=2: f16 per-head col-major [b*H+h][64][L]     (V, pre-transposed)
// ---------------------------------------------------------------------------
template<int EPI>
__device__ __forceinline__
void gemm_body(char* As, char* Bs, const f16* __restrict__ A,
               const f16* __restrict__ BT, const float* __restrict__ bias,
               void* __restrict__ OutP)
{
    const int tid = threadIdx.x, lane = tid & 63, wid = tid >> 6;
    const int g = lane >> 4, ql = lane & 15;
    const int wm = wid >> 1, wn = wid & 1;
    const int bid = blockIdx.x;
    const int sb = (bid & 7) * 32 + (bid >> 3);    // XCD swizzle (256 blocks)
    const int rowBase = (sb >> 2) * 128, colBase = (sb & 3) * 128;

    auto stage = [&](int p, int buf) {
        const int kt = p * 32;
        #pragma unroll
        for (int i = 0; i < 2; ++i) {
            const int xl = i * 4096 + wid * 1024 + lane * 16;
            const int xs = swz(xl);
            const int r = xs >> 6, cb = xs & 63;
            const char* asrc;
            if (EPI == 1) {
                const int m = rowBase + r, b = m >> 11, qq = m & 2047;
                const int kp = kt * 2 + cb;
                asrc = (const char*)A +
                       (((size_t)((b * 8 + (kp >> 7)) * 2048 + qq)) << 7) + (kp & 127);
            } else {
                asrc = (const char*)(A + (size_t)(rowBase + r) * DD + kt) + cb;
            }
            gload16(asrc, As + buf * 8192 + xl);
            gload16((const char*)(BT + (size_t)(colBase + r) * DD + kt) + cb,
                    Bs + buf * 8192 + xl);
        }
    };

    const f32x4 zero = {0.f, 0.f, 0.f, 0.f};
    f32x4 acc[4][4];
    #pragma unroll
    for (int i = 0; i < 4; ++i)
        #pragma unroll
        for (int j = 0; j < 4; ++j) acc[i][j] = zero;

    stage(0, 0);

    for (int p = 0; p < 16; ++p) {
        const int buf = p & 1;
        wait_barrier();                 // own stage(p) landed; all waves synced
        if (p < 15) stage(p + 1, buf ^ 1);   // stays in flight across next barrier
        const char* as = As + buf * 8192;
        const char* bs = Bs + buf * 8192;
        f16x8 af[4], bf[4];
        #pragma unroll
        for (int mf = 0; mf < 4; ++mf)
            af[mf] = *(const f16x8*)(as + swz((wm * 64 + mf * 16 + ql) * 64 + g * 16));
        #pragma unroll
        for (int nf = 0; nf < 4; ++nf)
            bf[nf] = *(const f16x8*)(bs + swz((wn * 64 + nf * 16 + ql) * 64 + g * 16));
        __builtin_amdgcn_s_setprio(1);
        #pragma unroll
        for (int mf = 0; mf < 4; ++mf)
            #pragma unroll
            for (int nf = 0; nf < 4; ++nf)
                acc[mf][nf] = __builtin_amdgcn_mfma_f32_16x16x32_f16(af[mf], bf[nf], acc[mf][nf], 0, 0, 0);
        __builtin_amdgcn_s_setprio(0);
    }

    #pragma unroll
    for (int nf = 0; nf < 4; ++nf) {
        const int n = colBase + wn * 64 + nf * 16 + ql;
        const float bn = bias[n];
        #pragma unroll
        for (int mf = 0; mf < 4; ++mf) {
            const int m0 = rowBase + wm * 64 + mf * 16 + g * 4;
            if (EPI == 2) {
                const int b = m0 >> 11, l0 = m0 & 2047;
                const int kd = n >> 3, hh = n & 7;
                f16x4v o = {(f16)(acc[mf][nf][0] + bn), (f16)(acc[mf][nf][1] + bn),
                            (f16)(acc[mf][nf][2] + bn), (f16)(acc[mf][nf][3] + bn)};
                *(f16x4v*)((f16*)OutP + ((size_t)(b * HH + hh) * KDIM + kd) * LL + l0) = o;
            } else {
                #pragma unroll
                for (int r = 0; r < 4; ++r) {
                    const int m = m0 + r;
                    const float v = acc[mf][nf][r] + bn;
                    if (EPI == 0) {
                        const int b = m >> 11, lr = m & 2047;
                        const int kd = n >> 3, hh = n & 7;
                        ((f16*)OutP)[((size_t)(b * HH + hh) * LL + lr) * KDIM + kd] = (f16)v;
                    } else {
                        ((float*)OutP)[(size_t)m * DD + n] = v;
                    }
                }
            }
        }
    }
}

__global__ __launch_bounds__(256)
void gemm_qkv(const f16* Xq, const f16* Xk, const f16* Xv,
              const f16* WTq, const f16* WTk, const f16* WTv,
              const float* bq, const float* bk, const float* bv,
              f16* Qh, f16* Kh, f16* VhT)
{
    __shared__ __align__(16) char As[2 * 128 * 32 * 2];
    __shared__ __align__(16) char Bs[2 * 128 * 32 * 2];
    const int z = blockIdx.z;
    if (z == 0)      gemm_body<0>(As, Bs, Xq, WTq, bq, Qh);
    else if (z == 1) gemm_body<0>(As, Bs, Xk, WTk, bk, Kh);
    else             gemm_body<2>(As, Bs, Xv, WTv, bv, VhT);
}

__global__ __launch_bounds__(256)
void gemm_out(const f16* A, const f16* BT, const float* bias, float* Out)
{
    __shared__ __align__(16) char As[2 * 128 * 32 * 2];
    __shared__ __align__(16) char Bs[2 * 128 * 32 * 2];
    gemm_body<1>(As, Bs, A, BT, bias, Out);
}

// ---------------------------------------------------------------------------
// MFMA flash attention. 2-wave blocks, QB=32 (16 q-rows/wave), KVBLK=64,
// single-buffered K/V, 2 barriers/tile. LDS = 8K(K)+8K(V)+4K(P) = 20 KB ->
// ~8 blocks/CU; 8 independently-phased blocks smooth VALU/MFMA/LDS demand.
// Transposed dataflow (S^T / O^T): softmax reduction axis lane-local (q=ql).
// Q,K in [bh][L][64]; V in [bh][64][L]; O in [bh][L][64] (packed 8B stores).
// ---------------------------------------------------------------------------
__global__ __launch_bounds__(128, 4)
void attn_f16(const f16* __restrict__ Qh, const f16* __restrict__ Kh,
              const f16* __restrict__ VhT, f16* __restrict__ Ob)
{
    __shared__ __align__(16) char k_s[64 * 128];   // [key][kd] swizzled, 8KB
    __shared__ __align__(16) char v_s[64 * 128];   // [kd][key] swizzled, 8KB
    __shared__ __align__(16) char p_s[2 * 2048];   // per-wave P^T, swizzled

    const int tid = threadIdx.x, lane = tid & 63, wid = tid >> 6;  // wid 0..1
    const int g = lane >> 4, ql = lane & 15;
    char* pw = p_s + wid * 2048;

    // XCD swizzle: 256 consecutive sb (4 bh) per XCD -> K/V L2-resident
    const int bid = blockIdx.x;                    // 0..2047
    const int sb = (bid & 7) * 256 + (bid >> 3);
    const int qt = sb & 63, bh = sb >> 6;

    const f16*  Qb = Qh + (size_t)bh * LL * KDIM;
    const char* Kb = (const char*)(Kh + (size_t)bh * LL * KDIM);
    const char* Vb = (const char*)(VhT + (size_t)bh * KDIM * LL);
    const int q0 = qt * 32 + wid * 16;

    auto stage = [&](int t) {
        const int kv = t * 64;
        #pragma unroll
        for (int i = 0; i < 4; ++i) {
            const int xl = i * 2048 + wid * 1024 + lane * 16;
            const int xs = swz(xl);
            gload16(Kb + (size_t)kv * 128 + xs, k_s + xl);
            gload16(Vb + (size_t)(xs >> 7) * (LL * 2) + (size_t)kv * 2 + (xs & 127),
                    v_s + xl);
        }
    };

    // Q fragment (B-operand: col=q, k=kd), scaled by 1/8 * log2(e)
    const f16 qscale = (f16)(0.125f * 1.44269504089f);
    f16x8 qfr[2];
    #pragma unroll
    for (int kb = 0; kb < 2; ++kb) {
        qfr[kb] = *(const f16x8*)(Qb + (size_t)(q0 + ql) * KDIM + kb * 32 + g * 8);
        qfr[kb] *= qscale;
    }

    const f32x4 zero = {0.f, 0.f, 0.f, 0.f};
    f32x4 acc[4];
    #pragma unroll
    for (int n = 0; n < 4; ++n) acc[n] = zero;
    float m_r = -1e30f, l_r = 0.f;

    for (int t = 0; t < 32; ++t) {
        stage(t);
        __syncthreads();                       // staging landed (vmcnt drain)

        // S^T = K Q^T : col = q (lane-local), rows = 64 keys
        f32x4 s[4];
        __builtin_amdgcn_s_setprio(1);
        #pragma unroll
        for (int kf = 0; kf < 4; ++kf) {
            f16x8 kfr0 = *(const f16x8*)(k_s + swz((kf * 16 + ql) * 128 + g * 16));
            f16x8 kfr1 = *(const f16x8*)(k_s + swz((kf * 16 + ql) * 128 + 64 + g * 16));
            f32x4 z = zero;
            z = __builtin_amdgcn_mfma_f32_16x16x32_f16(kfr0, qfr[0], z, 0, 0, 0);
            z = __builtin_amdgcn_mfma_f32_16x16x32_f16(kfr1, qfr[1], z, 0, 0, 0);
            s[kf] = z;
        }
        __builtin_amdgcn_s_setprio(0);

        // online softmax with defer-max (THR=8 in exp2 domain); max3 tree
        float a0 = fmaxf(fmaxf(s[0][0], s[0][1]), s[0][2]);
        float a1 = fmaxf(fmaxf(s[0][3], s[1][0]), s[1][1]);
        float a2 = fmaxf(fmaxf(s[1][2], s[1][3]), s[2][0]);
        float a3 = fmaxf(fmaxf(s[2][1], s[2][2]), s[2][3]);
        float a4 = fmaxf(fmaxf(s[3][0], s[3][1]), s[3][2]);
        float mx = fmaxf(fmaxf(fmaxf(a0, a1), fmaxf(a2, a3)),
                         fmaxf(a4, s[3][3]));
        mx = fmaxf(mx, __shfl_xor(mx, 16));
        mx = fmaxf(mx, __shfl_xor(mx, 32));
        if (__any(mx > m_r + 8.f)) {
            const float mnew = fmaxf(m_r, mx);
            const float fsc = exp2f(m_r - mnew);
            m_r = mnew;
            l_r *= fsc;
            #pragma unroll
            for (int n = 0; n < 4; ++n) acc[n] *= fsc;
        }
        float ps = 0.f;
        #pragma unroll
        for (int kf = 0; kf < 4; ++kf) {
            const float p0 = exp2f(s[kf][0] - m_r);
            const float p1 = exp2f(s[kf][1] - m_r);
            const float p2 = exp2f(s[kf][2] - m_r);
            const float p3 = exp2f(s[kf][3] - m_r);
            ps += (p0 + p1) + (p2 + p3);
            f16x4v pk = {(f16)p0, (f16)p1, (f16)p2, (f16)p3};
            *(f16x4v*)(pw + swz(ql * 128 + kf * 32 + g * 8)) = pk;
        }
        l_r += ps;   // per-lane partial; cross-lane reduced once at epilogue

        // O^T += V^T P^T
        __builtin_amdgcn_s_setprio(1);
        #pragma unroll
        for (int kb = 0; kb < 2; ++kb) {
            f16x8 pf = *(const f16x8*)(pw + swz(ql * 128 + kb * 64 + g * 16));
            #pragma unroll
            for (int n = 0; n < 4; ++n) {
                f16x8 vf = *(const f16x8*)(v_s + swz((n * 16 + ql) * 128
                                                     + kb * 64 + g * 16));
                acc[n] = __builtin_amdgcn_mfma_f32_16x16x32_f16(vf, pf, acc[n], 0, 0, 0);
            }
        }
        __builtin_amdgcn_s_setprio(0);
        __syncthreads();                       // reads done -> safe to restage
    }

    // epilogue: reduce l across the 4 g-lanes (linear in all rescales), store
    l_r += __shfl_xor(l_r, 16);
    l_r += __shfl_xor(l_r, 32);
    const float inv = 1.f / l_r;
    const int q = q0 + ql;
    f16* orow = Ob + ((size_t)bh * LL + q) * KDIM;
    #pragma unroll
    for (int n = 0; n < 4; ++n) {
        f16x4v o = {(f16)(acc[n][0] * inv), (f16)(acc[n][1] * inv),
                    (f16)(acc[n][2] * inv), (f16)(acc[n][3] * inv)};
        *(f16x4v*)(orow + n * 16 + g * 4) = o;
    }
}

// ---------------------------------------------------------------------------
extern "C" void kernel_launch(void* const* d_in, const int* in_sizes, int n_in,
                              void* d_out, int out_size, void* d_ws, size_t ws_size,
                              hipStream_t stream)
{
    const float* query = (const float*)d_in[0];
    const float* key   = (const float*)d_in[1];
    const float* value = (const float*)d_in[2];
    const int* wq = (const int*)d_in[3];
    const int* wk = (const int*)d_in[4];
    const int* wv = (const int*)d_in[5];
    const int* wo = (const int*)d_in[6];
    const float* bq = (const float*)d_in[7];
    const float* bk = (const float*)d_in[8];
    const float* bv = (const float*)d_in[9];
    const float* bo = (const float*)d_in[10];
    const float* scale_q = (const float*)d_in[11];
    const float* scale_k = (const float*)d_in[12];
    const float* scale_v = (const float*)d_in[13];
    const float* scale_o = (const float*)d_in[14];
    const float* zp_q = (const float*)d_in[15];
    const float* zp_k = (const float*)d_in[16];
    const float* zp_v = (const float*)d_in[17];
    const float* zp_o = (const float*)d_in[18];

    const size_t MD = (size_t)BB * LL * DD;       // 4.19M
    const size_t WT_SZ = (size_t)DD * DD;

    f16* Xq  = (f16*)d_ws;
    f16* Xk  = Xq + MD;
    f16* Xv  = Xk + MD;
    f16* WTq = Xv + MD;
    f16* WTk = WTq + WT_SZ;
    f16* WTv = WTk + WT_SZ;
    f16* WTo = WTv + WT_SZ;
    f16* Qh  = WTo + WT_SZ;
    f16* Kh  = Qh + MD;
    f16* VhT = Kh + MD;
    f16* Ob  = VhT + MD;   // [b][h][q][64]

    prologue<<<1024 + 3 * 4096, 256, 0, stream>>>(
        wq, wk, wv, wo, scale_q, scale_k, scale_v, scale_o,
        zp_q, zp_k, zp_v, zp_o, WTq, WTk, WTv, WTo,
        query, key, value, Xq, Xk, Xv);

    dim3 gg(256, 1, 3);
    gemm_qkv<<<gg, 256, 0, stream>>>(Xq, Xk, Xv, WTq, WTk, WTv,
                                     bq, bk, bv, Qh, Kh, VhT);

    attn_f16<<<2048, 128, 0, stream>>>(Qh, Kh, VhT, Ob);

    gemm_out<<<256, 256, 0, stream>>>(Ob, WTo, bo, (float*)d_out);
}

// Round 8
// 154.449 us; speedup vs baseline: 1.0165x; 1.0165x over previous
//
#include <hip/hip_runtime.h>
#include <math.h>
#include <stdint.h>

#define BB 4
#define LL 2048
#define DD 512
#define KDIM 64
#define HH 8

typedef _Float16 f16;
typedef f16 f16x8 __attribute__((ext_vector_type(8)));
typedef f16 f16x4v __attribute__((ext_vector_type(4)));
typedef float f32x4 __attribute__((ext_vector_type(4)));

// Involutive XOR swizzle for 128B-row (attn) and 64B-row (GEMM) LDS tiles.
__device__ __forceinline__ int swz(int x) { return x ^ (((x >> 7) & 7) << 4); }

__device__ __forceinline__ void gload16(const void* g, void* l) {
    __builtin_amdgcn_global_load_lds(
        (const __attribute__((address_space(1))) void*)g,
        (__attribute__((address_space(3))) void*)l, 16, 0, 0);
}

// Counted-drain barrier (GEMM pipeline): wait own staging loads, raw barrier.
__device__ __forceinline__ void wait_barrier() {
    asm volatile("s_waitcnt vmcnt(0)" ::: "memory");
    __builtin_amdgcn_s_barrier();
}

// ---------------------------------------------------------------------------
// Prologue: weight dequant+transpose (4 weights) AND fp32->fp16 casts (3
// activations) in ONE launch. 1D grid: bid<1024 -> prep, else cast.
// WO (zi==3): k-index permuted k' = (k&7)*64 + (k>>3) so the final GEMM can
// read the attention output in per-head [b][h][q][64] layout.
// ---------------------------------------------------------------------------
__global__ __launch_bounds__(256)
void prologue(const int* __restrict__ w0, const int* __restrict__ w1,
              const int* __restrict__ w2, const int* __restrict__ w3,
              const float* s0, const float* s1, const float* s2, const float* s3,
              const float* z0, const float* z1, const float* z2, const float* z3,
              f16* o0, f16* o1, f16* o2, f16* o3,
              const float* __restrict__ xq, const float* __restrict__ xk,
              const float* __restrict__ xv, f16* cq, f16* ck, f16* cv)
{
    __shared__ float t[32][33];
    const int bid = blockIdx.x;
    if (bid < 1024) {
        const int zi = bid >> 8, rem = bid & 255;
        const int* W = zi == 0 ? w0 : zi == 1 ? w1 : zi == 2 ? w2 : w3;
        const float sc = *(zi == 0 ? s0 : zi == 1 ? s1 : zi == 2 ? s2 : s3);
        const float zp = *(zi == 0 ? z0 : zi == 1 ? z1 : zi == 2 ? z2 : z3);
        f16* WT = zi == 0 ? o0 : zi == 1 ? o1 : zi == 2 ? o2 : o3;
        const int n0 = (rem & 15) * 32, k0 = (rem >> 4) * 32;
        const int x = threadIdx.x & 31, y = threadIdx.x >> 5;  // 32 x 8
        #pragma unroll
        for (int i = 0; i < 32; i += 8)
            t[y + i][x] = ((float)W[(size_t)(k0 + y + i) * DD + n0 + x] - zp) * sc;
        __syncthreads();
        if (zi == 3) {
            const int k = k0 + x;
            const int kp = (k & 7) * 64 + (k >> 3);
            #pragma unroll
            for (int i = 0; i < 32; i += 8)
                WT[(size_t)(n0 + y + i) * DD + kp] = (f16)t[x][y + i];
        } else {
            #pragma unroll
            for (int i = 0; i < 32; i += 8)
                WT[(size_t)(n0 + y + i) * DD + k0 + x] = (f16)t[x][y + i];
        }
    } else {
        const int c = bid - 1024;
        const int yi = c >> 12, xb = c & 4095;
        const float* in = yi == 0 ? xq : yi == 1 ? xk : xv;
        f16* out = yi == 0 ? cq : yi == 1 ? ck : cv;
        const int i = (xb * 256 + threadIdx.x) * 4;
        float4 v = *(const float4*)(in + i);
        f16x4v o = {(f16)v.x, (f16)v.y, (f16)v.z, (f16)v.w};
        *(f16x4v*)(out + i) = o;
    }
}

// ---------------------------------------------------------------------------
// MFMA GEMM body: Out[M=8192][N=512] = A[M][512] @ WT^T + bias.
// 128x128 tile, BK=32, 4 waves (2x2), 4x4 16x16x32 frags per wave.
// Double-buffered LDS, counted-vmcnt pipeline (one barrier per K-step).
// EPI=0: f16 per-head row-major [b*H+h][L][64]     (Q, K)
// EPI=1: fp32 [M][N]; A is per-head [b][h][q][64] with permuted-k weights
// EPI=2: f16 per-head col-major [b*H+h][64][L]     (V, pre-transposed)
// ---------------------------------------------------------------------------
template<int EPI>
__device__ __forceinline__
void gemm_body(char* As, char* Bs, const f16* __restrict__ A,
               const f16* __restrict__ BT, const float* __restrict__ bias,
               void* __restrict__ OutP)
{
    const int tid = threadIdx.x, lane = tid & 63, wid = tid >> 6;
    const int g = lane >> 4, ql = lane & 15;
    const int wm = wid >> 1, wn = wid & 1;
    const int bid = blockIdx.x;
    const int sb = (bid & 7) * 32 + (bid >> 3);    // XCD swizzle (256 blocks)
    const int rowBase = (sb >> 2) * 128, colBase = (sb & 3) * 128;

    auto stage = [&](int p, int buf) {
        const int kt = p * 32;
        #pragma unroll
        for (int i = 0; i < 2; ++i) {
            const int xl = i * 4096 + wid * 1024 + lane * 16;
            const int xs = swz(xl);
            const int r = xs >> 6, cb = xs & 63;
            const char* asrc;
            if (EPI == 1) {
                const int m = rowBase + r, b = m >> 11, qq = m & 2047;
                const int kp = kt * 2 + cb;
                asrc = (const char*)A +
                       (((size_t)((b * 8 + (kp >> 7)) * 2048 + qq)) << 7) + (kp & 127);
            } else {
                asrc = (const char*)(A + (size_t)(rowBase + r) * DD + kt) + cb;
            }
            gload16(asrc, As + buf * 8192 + xl);
            gload16((const char*)(BT + (size_t)(colBase + r) * DD + kt) + cb,
                    Bs + buf * 8192 + xl);
        }
    };

    const f32x4 zero = {0.f, 0.f, 0.f, 0.f};
    f32x4 acc[4][4];
    #pragma unroll
    for (int i = 0; i < 4; ++i)
        #pragma unroll
        for (int j = 0; j < 4; ++j) acc[i][j] = zero;

    stage(0, 0);

    for (int p = 0; p < 16; ++p) {
        const int buf = p & 1;
        wait_barrier();                 // own stage(p) landed; all waves synced
        if (p < 15) stage(p + 1, buf ^ 1);   // stays in flight across next barrier
        const char* as = As + buf * 8192;
        const char* bs = Bs + buf * 8192;
        f16x8 af[4], bf[4];
        #pragma unroll
        for (int mf = 0; mf < 4; ++mf)
            af[mf] = *(const f16x8*)(as + swz((wm * 64 + mf * 16 + ql) * 64 + g * 16));
        #pragma unroll
        for (int nf = 0; nf < 4; ++nf)
            bf[nf] = *(const f16x8*)(bs + swz((wn * 64 + nf * 16 + ql) * 64 + g * 16));
        __builtin_amdgcn_s_setprio(1);
        #pragma unroll
        for (int mf = 0; mf < 4; ++mf)
            #pragma unroll
            for (int nf = 0; nf < 4; ++nf)
                acc[mf][nf] = __builtin_amdgcn_mfma_f32_16x16x32_f16(af[mf], bf[nf], acc[mf][nf], 0, 0, 0);
        __builtin_amdgcn_s_setprio(0);
    }

    #pragma unroll
    for (int nf = 0; nf < 4; ++nf) {
        const int n = colBase + wn * 64 + nf * 16 + ql;
        const float bn = bias[n];
        #pragma unroll
        for (int mf = 0; mf < 4; ++mf) {
            const int m0 = rowBase + wm * 64 + mf * 16 + g * 4;
            if (EPI == 2) {
                const int b = m0 >> 11, l0 = m0 & 2047;
                const int kd = n >> 3, hh = n & 7;
                f16x4v o = {(f16)(acc[mf][nf][0] + bn), (f16)(acc[mf][nf][1] + bn),
                            (f16)(acc[mf][nf][2] + bn), (f16)(acc[mf][nf][3] + bn)};
                *(f16x4v*)((f16*)OutP + ((size_t)(b * HH + hh) * KDIM + kd) * LL + l0) = o;
            } else {
                #pragma unroll
                for (int r = 0; r < 4; ++r) {
                    const int m = m0 + r;
                    const float v = acc[mf][nf][r] + bn;
                    if (EPI == 0) {
                        const int b = m >> 11, lr = m & 2047;
                        const int kd = n >> 3, hh = n & 7;
                        ((f16*)OutP)[((size_t)(b * HH + hh) * LL + lr) * KDIM + kd] = (f16)v;
                    } else {
                        ((float*)OutP)[(size_t)m * DD + n] = v;
                    }
                }
            }
        }
    }
}

__global__ __launch_bounds__(256)
void gemm_qkv(const f16* Xq, const f16* Xk, const f16* Xv,
              const f16* WTq, const f16* WTk, const f16* WTv,
              const float* bq, const float* bk, const float* bv,
              f16* Qh, f16* Kh, f16* VhT)
{
    __shared__ __align__(16) char As[2 * 128 * 32 * 2];
    __shared__ __align__(16) char Bs[2 * 128 * 32 * 2];
    const int z = blockIdx.z;
    if (z == 0)      gemm_body<0>(As, Bs, Xq, WTq, bq, Qh);
    else if (z == 1) gemm_body<0>(As, Bs, Xk, WTk, bk, Kh);
    else             gemm_body<2>(As, Bs, Xv, WTv, bv, VhT);
}

__global__ __launch_bounds__(256)
void gemm_out(const f16* A, const f16* BT, const float* bias, float* Out)
{
    __shared__ __align__(16) char As[2 * 128 * 32 * 2];
    __shared__ __align__(16) char Bs[2 * 128 * 32 * 2];
    gemm_body<1>(As, Bs, A, BT, bias, Out);
}

// ---------------------------------------------------------------------------
// MFMA flash attention. 2-wave blocks, QB=64 -> 32 q-rows per wave (2 q-frags)
// so each staged K/V tile byte serves 2x the output: per-work LDS/VALU halves.
// Single-buffered K/V, 2 barriers/tile; only 2 waves phase-locked.
// LDS = 8K(K)+8K(V)+8K(P) = 24 KB -> 4 blocks/CU (grid 1024).
// Transposed dataflow (S^T / O^T): softmax reduction axis lane-local (q=ql).
// Q,K in [bh][L][64]; V in [bh][64][L]; O in [bh][L][64] (packed 8B stores).
// ---------------------------------------------------------------------------
__global__ __launch_bounds__(128, 4)
void attn_f16(const f16* __restrict__ Qh, const f16* __restrict__ Kh,
              const f16* __restrict__ VhT, f16* __restrict__ Ob)
{
    __shared__ __align__(16) char k_s[64 * 128];   // [key][kd] swizzled, 8KB
    __shared__ __align__(16) char v_s[64 * 128];   // [kd][key] swizzled, 8KB
    __shared__ __align__(16) char p_s[2 * 4096];   // per-wave P^T [32 q][64 key]

    const int tid = threadIdx.x, lane = tid & 63, wid = tid >> 6;  // wid 0..1
    const int g = lane >> 4, ql = lane & 15;
    char* pw = p_s + wid * 4096;

    // XCD swizzle: 128 consecutive sb (4 bh) per XCD -> K/V L2-resident
    const int bid = blockIdx.x;                    // 0..1023
    const int sb = (bid & 7) * 128 + (bid >> 3);
    const int qt = sb & 31, bh = sb >> 5;

    const f16*  Qb = Qh + (size_t)bh * LL * KDIM;
    const char* Kb = (const char*)(Kh + (size_t)bh * LL * KDIM);
    const char* Vb = (const char*)(VhT + (size_t)bh * KDIM * LL);
    const int q0 = qt * 64 + wid * 32;

    auto stage = [&](int t) {
        const int kv = t * 64;
        #pragma unroll
        for (int i = 0; i < 4; ++i) {
            const int xl = i * 2048 + wid * 1024 + lane * 16;
            const int xs = swz(xl);
            gload16(Kb + (size_t)kv * 128 + xs, k_s + xl);
            gload16(Vb + (size_t)(xs >> 7) * (LL * 2) + (size_t)kv * 2 + (xs & 127),
                    v_s + xl);
        }
    };

    // Q fragments (B-operand: col=q, k=kd), scaled by 1/8 * log2(e)
    const f16 qscale = (f16)(0.125f * 1.44269504089f);
    f16x8 qfr[2][2];
    #pragma unroll
    for (int i2 = 0; i2 < 2; ++i2)
        #pragma unroll
        for (int kb = 0; kb < 2; ++kb) {
            qfr[i2][kb] = *(const f16x8*)(Qb + (size_t)(q0 + i2 * 16 + ql) * KDIM
                                          + kb * 32 + g * 8);
            qfr[i2][kb] *= qscale;
        }

    const f32x4 zero = {0.f, 0.f, 0.f, 0.f};
    f32x4 acc[2][4];
    float m_r[2], l_r[2];
    #pragma unroll
    for (int i2 = 0; i2 < 2; ++i2) {
        m_r[i2] = -1e30f; l_r[i2] = 0.f;
        #pragma unroll
        for (int n = 0; n < 4; ++n) acc[i2][n] = zero;
    }

    for (int t = 0; t < 32; ++t) {
        stage(t);
        __syncthreads();                       // staging landed (vmcnt drain)

        // K fragments shared across both q-frags
        f16x8 kfr[4][2];
        #pragma unroll
        for (int kf = 0; kf < 4; ++kf) {
            kfr[kf][0] = *(const f16x8*)(k_s + swz((kf * 16 + ql) * 128 + g * 16));
            kfr[kf][1] = *(const f16x8*)(k_s + swz((kf * 16 + ql) * 128 + 64 + g * 16));
        }

        #pragma unroll
        for (int i2 = 0; i2 < 2; ++i2) {
            // S^T = K Q^T : col = q (lane-local), rows = 64 keys
            f32x4 s[4];
            __builtin_amdgcn_s_setprio(1);
            #pragma unroll
            for (int kf = 0; kf < 4; ++kf) {
                f32x4 z = zero;
                z = __builtin_amdgcn_mfma_f32_16x16x32_f16(kfr[kf][0], qfr[i2][0], z, 0, 0, 0);
                z = __builtin_amdgcn_mfma_f32_16x16x32_f16(kfr[kf][1], qfr[i2][1], z, 0, 0, 0);
                s[kf] = z;
            }
            __builtin_amdgcn_s_setprio(0);

            // online softmax with defer-max (THR=8 in exp2 domain); max3 tree
            float a0 = fmaxf(fmaxf(s[0][0], s[0][1]), s[0][2]);
            float a1 = fmaxf(fmaxf(s[0][3], s[1][0]), s[1][1]);
            float a2 = fmaxf(fmaxf(s[1][2], s[1][3]), s[2][0]);
            float a3 = fmaxf(fmaxf(s[2][1], s[2][2]), s[2][3]);
            float a4 = fmaxf(fmaxf(s[3][0], s[3][1]), s[3][2]);
            float mx = fmaxf(fmaxf(fmaxf(a0, a1), fmaxf(a2, a3)),
                             fmaxf(a4, s[3][3]));
            mx = fmaxf(mx, __shfl_xor(mx, 16));
            mx = fmaxf(mx, __shfl_xor(mx, 32));
            if (__any(mx > m_r[i2] + 8.f)) {
                const float mnew = fmaxf(m_r[i2], mx);
                const float fsc = exp2f(m_r[i2] - mnew);
                m_r[i2] = mnew;
                l_r[i2] *= fsc;
                #pragma unroll
                for (int n = 0; n < 4; ++n) acc[i2][n] *= fsc;
            }
            float ps = 0.f;
            #pragma unroll
            for (int kf = 0; kf < 4; ++kf) {
                const float p0 = exp2f(s[kf][0] - m_r[i2]);
                const float p1 = exp2f(s[kf][1] - m_r[i2]);
                const float p2 = exp2f(s[kf][2] - m_r[i2]);
                const float p3 = exp2f(s[kf][3] - m_r[i2]);
                ps += (p0 + p1) + (p2 + p3);
                f16x4v pk = {(f16)p0, (f16)p1, (f16)p2, (f16)p3};
                *(f16x4v*)(pw + swz((i2 * 16 + ql) * 128 + kf * 32 + g * 8)) = pk;
            }
            l_r[i2] += ps;   // per-lane partial; reduced once at epilogue
        }

        // O^T += V^T P^T  (V-frags shared across both q-frags)
        __builtin_amdgcn_s_setprio(1);
        #pragma unroll
        for (int kb = 0; kb < 2; ++kb) {
            f16x8 pf[2];
            #pragma unroll
            for (int i2 = 0; i2 < 2; ++i2)
                pf[i2] = *(const f16x8*)(pw + swz((i2 * 16 + ql) * 128 + kb * 64 + g * 16));
            #pragma unroll
            for (int n = 0; n < 4; ++n) {
                f16x8 vf = *(const f16x8*)(v_s + swz((n * 16 + ql) * 128
                                                     + kb * 64 + g * 16));
                #pragma unroll
                for (int i2 = 0; i2 < 2; ++i2)
                    acc[i2][n] = __builtin_amdgcn_mfma_f32_16x16x32_f16(vf, pf[i2], acc[i2][n], 0, 0, 0);
            }
        }
        __builtin_amdgcn_s_setprio(0);
        __syncthreads();                       // reads done -> safe to restage
    }

    // epilogue: reduce l across the 4 g-lanes (linear in all rescales), store
    #pragma unroll
    for (int i2 = 0; i2 < 2; ++i2) {
        float l = l_r[i2];
        l += __shfl_xor(l, 16);
        l += __shfl_xor(l, 32);
        const float inv = 1.f / l;
        const int q = q0 + i2 * 16 + ql;
        f16* orow = Ob + ((size_t)bh * LL + q) * KDIM;
        #pragma unroll
        for (int n = 0; n < 4; ++n) {
            f16x4v o = {(f16)(acc[i2][n][0] * inv), (f16)(acc[i2][n][1] * inv),
                        (f16)(acc[i2][n][2] * inv), (f16)(acc[i2][n][3] * inv)};
            *(f16x4v*)(orow + n * 16 + g * 4) = o;
        }
    }
}

// ---------------------------------------------------------------------------
extern "C" void kernel_launch(void* const* d_in, const int* in_sizes, int n_in,
                              void* d_out, int out_size, void* d_ws, size_t ws_size,
                              hipStream_t stream)
{
    const float* query = (const float*)d_in[0];
    const float* key   = (const float*)d_in[1];
    const float* value = (const float*)d_in[2];
    const int* wq = (const int*)d_in[3];
    const int* wk = (const int*)d_in[4];
    const int* wv = (const int*)d_in[5];
    const int* wo = (const int*)d_in[6];
    const float* bq = (const float*)d_in[7];
    const float* bk = (const float*)d_in[8];
    const float* bv = (const float*)d_in[9];
    const float* bo = (const float*)d_in[10];
    const float* scale_q = (const float*)d_in[11];
    const float* scale_k = (const float*)d_in[12];
    const float* scale_v = (const float*)d_in[13];
    const float* scale_o = (const float*)d_in[14];
    const float* zp_q = (const float*)d_in[15];
    const float* zp_k = (const float*)d_in[16];
    const float* zp_v = (const float*)d_in[17];
    const float* zp_o = (const float*)d_in[18];

    const size_t MD = (size_t)BB * LL * DD;       // 4.19M
    const size_t WT_SZ = (size_t)DD * DD;

    f16* Xq  = (f16*)d_ws;
    f16* Xk  = Xq + MD;
    f16* Xv  = Xk + MD;
    f16* WTq = Xv + MD;
    f16* WTk = WTq + WT_SZ;
    f16* WTv = WTk + WT_SZ;
    f16* WTo = WTv + WT_SZ;
    f16* Qh  = WTo + WT_SZ;
    f16* Kh  = Qh + MD;
    f16* VhT = Kh + MD;
    f16* Ob  = VhT + MD;   // [b][h][q][64]

    prologue<<<1024 + 3 * 4096, 256, 0, stream>>>(
        wq, wk, wv, wo, scale_q, scale_k, scale_v, scale_o,
        zp_q, zp_k, zp_v, zp_o, WTq, WTk, WTv, WTo,
        query, key, value, Xq, Xk, Xv);

    dim3 gg(256, 1, 3);
    gemm_qkv<<<gg, 256, 0, stream>>>(Xq, Xk, Xv, WTq, WTk, WTv,
                                     bq, bk, bv, Qh, Kh, VhT);

    attn_f16<<<1024, 128, 0, stream>>>(Qh, Kh, VhT, Ob);

    gemm_out<<<256, 256, 0, stream>>>(Ob, WTo, bo, (float*)d_out);
}

// Round 9
// 141.311 us; speedup vs baseline: 1.1110x; 1.0930x over previous
//
#include <hip/hip_runtime.h>
#include <math.h>
#include <stdint.h>

#define BB 4
#define LL 2048
#define DD 512
#define KDIM 64
#define HH 8

typedef _Float16 f16;
typedef f16 f16x8 __attribute__((ext_vector_type(8)));
typedef f16 f16x4v __attribute__((ext_vector_type(4)));
typedef float f32x4 __attribute__((ext_vector_type(4)));

// Involutive XOR swizzles: swz7 for 128B-row LDS tiles, swz8 for 256B rows.
__device__ __forceinline__ int swz7(int x) { return x ^ (((x >> 7) & 7) << 4); }
__device__ __forceinline__ int swz8(int x) { return x ^ (((x >> 8) & 7) << 4); }

__device__ __forceinline__ void gload16(const void* g, void* l) {
    __builtin_amdgcn_global_load_lds(
        (const __attribute__((address_space(1))) void*)g,
        (__attribute__((address_space(3))) void*)l, 16, 0, 0);
}

// Counted-drain barrier (GEMM pipeline): wait own staging loads, raw barrier.
__device__ __forceinline__ void wait_barrier() {
    asm volatile("s_waitcnt vmcnt(0)" ::: "memory");
    __builtin_amdgcn_s_barrier();
}

// ---------------------------------------------------------------------------
// Prologue: weight dequant+transpose (4 weights) AND fp32->fp16 casts (3
// activations) in ONE launch. 1D grid: bid<1024 -> prep, else cast.
// WO (zi==3): k-index permuted k' = (k&7)*64 + (k>>3) so the final GEMM can
// read the attention output in per-head [b][h][q][64] layout.
// ---------------------------------------------------------------------------
__global__ __launch_bounds__(256)
void prologue(const int* __restrict__ w0, const int* __restrict__ w1,
              const int* __restrict__ w2, const int* __restrict__ w3,
              const float* s0, const float* s1, const float* s2, const float* s3,
              const float* z0, const float* z1, const float* z2, const float* z3,
              f16* o0, f16* o1, f16* o2, f16* o3,
              const float* __restrict__ xq, const float* __restrict__ xk,
              const float* __restrict__ xv, f16* cq, f16* ck, f16* cv)
{
    __shared__ float t[32][33];
    const int bid = blockIdx.x;
    if (bid < 1024) {
        const int zi = bid >> 8, rem = bid & 255;
        const int* W = zi == 0 ? w0 : zi == 1 ? w1 : zi == 2 ? w2 : w3;
        const float sc = *(zi == 0 ? s0 : zi == 1 ? s1 : zi == 2 ? s2 : s3);
        const float zp = *(zi == 0 ? z0 : zi == 1 ? z1 : zi == 2 ? z2 : z3);
        f16* WT = zi == 0 ? o0 : zi == 1 ? o1 : zi == 2 ? o2 : o3;
        const int n0 = (rem & 15) * 32, k0 = (rem >> 4) * 32;
        const int x = threadIdx.x & 31, y = threadIdx.x >> 5;  // 32 x 8
        #pragma unroll
        for (int i = 0; i < 32; i += 8)
            t[y + i][x] = ((float)W[(size_t)(k0 + y + i) * DD + n0 + x] - zp) * sc;
        __syncthreads();
        if (zi == 3) {
            const int k = k0 + x;
            const int kp = (k & 7) * 64 + (k >> 3);
            #pragma unroll
            for (int i = 0; i < 32; i += 8)
                WT[(size_t)(n0 + y + i) * DD + kp] = (f16)t[x][y + i];
        } else {
            #pragma unroll
            for (int i = 0; i < 32; i += 8)
                WT[(size_t)(n0 + y + i) * DD + k0 + x] = (f16)t[x][y + i];
        }
    } else {
        const int c = bid - 1024;
        const int yi = c >> 12, xb = c & 4095;
        const float* in = yi == 0 ? xq : yi == 1 ? xk : xv;
        f16* out = yi == 0 ? cq : yi == 1 ? ck : cv;
        const int i = (xb * 256 + threadIdx.x) * 4;
        float4 v = *(const float4*)(in + i);
        f16x4v o = {(f16)v.x, (f16)v.y, (f16)v.z, (f16)v.w};
        *(f16x4v*)(out + i) = o;
    }
}

// ---------------------------------------------------------------------------
// MFMA GEMM body: Out[M=8192][N=512] = A[M][512] @ WT^T + bias.
// 128x128 tile, BK=32, 4 waves (2x2), 4x4 16x16x32 frags per wave.
// Double-buffered LDS, counted-vmcnt pipeline (one barrier per K-step).
// EPI=0: f16 per-head row-major [b*H+h][L][64]     (Q, K)
// EPI=1: fp32 [M][N]; A is per-head [b][h][q][64] with permuted-k weights
// EPI=2: f16 per-head col-major [b*H+h][64][L]     (V, pre-transposed)
// ---------------------------------------------------------------------------
template<int EPI>
__device__ __forceinline__
void gemm_body(char* As, char* Bs, const f16* __restrict__ A,
               const f16* __restrict__ BT, const float* __restrict__ bias,
               void* __restrict__ OutP)
{
    const int tid = threadIdx.x, lane = tid & 63, wid = tid >> 6;
    const int g = lane >> 4, ql = lane & 15;
    const int wm = wid >> 1, wn = wid & 1;
    const int bid = blockIdx.x;
    const int sb = (bid & 7) * 32 + (bid >> 3);    // XCD swizzle (256 blocks)
    const int rowBase = (sb >> 2) * 128, colBase = (sb & 3) * 128;

    auto stage = [&](int p, int buf) {
        const int kt = p * 32;
        #pragma unroll
        for (int i = 0; i < 2; ++i) {
            const int xl = i * 4096 + wid * 1024 + lane * 16;
            const int xs = swz7(xl);
            const int r = xs >> 6, cb = xs & 63;
            const char* asrc;
            if (EPI == 1) {
                const int m = rowBase + r, b = m >> 11, qq = m & 2047;
                const int kp = kt * 2 + cb;
                asrc = (const char*)A +
                       (((size_t)((b * 8 + (kp >> 7)) * 2048 + qq)) << 7) + (kp & 127);
            } else {
                asrc = (const char*)(A + (size_t)(rowBase + r) * DD + kt) + cb;
            }
            gload16(asrc, As + buf * 8192 + xl);
            gload16((const char*)(BT + (size_t)(colBase + r) * DD + kt) + cb,
                    Bs + buf * 8192 + xl);
        }
    };

    const f32x4 zero = {0.f, 0.f, 0.f, 0.f};
    f32x4 acc[4][4];
    #pragma unroll
    for (int i = 0; i < 4; ++i)
        #pragma unroll
        for (int j = 0; j < 4; ++j) acc[i][j] = zero;

    stage(0, 0);

    for (int p = 0; p < 16; ++p) {
        const int buf = p & 1;
        wait_barrier();                 // own stage(p) landed; all waves synced
        if (p < 15) stage(p + 1, buf ^ 1);   // stays in flight across next barrier
        const char* as = As + buf * 8192;
        const char* bs = Bs + buf * 8192;
        f16x8 af[4], bf[4];
        #pragma unroll
        for (int mf = 0; mf < 4; ++mf)
            af[mf] = *(const f16x8*)(as + swz7((wm * 64 + mf * 16 + ql) * 64 + g * 16));
        #pragma unroll
        for (int nf = 0; nf < 4; ++nf)
            bf[nf] = *(const f16x8*)(bs + swz7((wn * 64 + nf * 16 + ql) * 64 + g * 16));
        __builtin_amdgcn_s_setprio(1);
        #pragma unroll
        for (int mf = 0; mf < 4; ++mf)
            #pragma unroll
            for (int nf = 0; nf < 4; ++nf)
                acc[mf][nf] = __builtin_amdgcn_mfma_f32_16x16x32_f16(af[mf], bf[nf], acc[mf][nf], 0, 0, 0);
        __builtin_amdgcn_s_setprio(0);
    }

    #pragma unroll
    for (int nf = 0; nf < 4; ++nf) {
        const int n = colBase + wn * 64 + nf * 16 + ql;
        const float bn = bias[n];
        #pragma unroll
        for (int mf = 0; mf < 4; ++mf) {
            const int m0 = rowBase + wm * 64 + mf * 16 + g * 4;
            if (EPI == 2) {
                const int b = m0 >> 11, l0 = m0 & 2047;
                const int kd = n >> 3, hh = n & 7;
                f16x4v o = {(f16)(acc[mf][nf][0] + bn), (f16)(acc[mf][nf][1] + bn),
                            (f16)(acc[mf][nf][2] + bn), (f16)(acc[mf][nf][3] + bn)};
                *(f16x4v*)((f16*)OutP + ((size_t)(b * HH + hh) * KDIM + kd) * LL + l0) = o;
            } else {
                #pragma unroll
                for (int r = 0; r < 4; ++r) {
                    const int m = m0 + r;
                    const float v = acc[mf][nf][r] + bn;
                    if (EPI == 0) {
                        const int b = m >> 11, lr = m & 2047;
                        const int kd = n >> 3, hh = n & 7;
                        ((f16*)OutP)[((size_t)(b * HH + hh) * LL + lr) * KDIM + kd] = (f16)v;
                    } else {
                        ((float*)OutP)[(size_t)m * DD + n] = v;
                    }
                }
            }
        }
    }
}

__global__ __launch_bounds__(256)
void gemm_qkv(const f16* Xq, const f16* Xk, const f16* Xv,
              const f16* WTq, const f16* WTk, const f16* WTv,
              const float* bq, const float* bk, const float* bv,
              f16* Qh, f16* Kh, f16* VhT)
{
    __shared__ __align__(16) char As[2 * 128 * 32 * 2];
    __shared__ __align__(16) char Bs[2 * 128 * 32 * 2];
    const int z = blockIdx.z;
    if (z == 0)      gemm_body<0>(As, Bs, Xq, WTq, bq, Qh);
    else if (z == 1) gemm_body<0>(As, Bs, Xk, WTk, bk, Kh);
    else             gemm_body<2>(As, Bs, Xv, WTv, bv, VhT);
}

__global__ __launch_bounds__(256)
void gemm_out(const f16* A, const f16* BT, const float* bias, float* Out)
{
    __shared__ __align__(16) char As[2 * 128 * 32 * 2];
    __shared__ __align__(16) char Bs[2 * 128 * 32 * 2];
    gemm_body<1>(As, Bs, A, BT, bias, Out);
}

// ---------------------------------------------------------------------------
// MFMA flash attention. 8-wave blocks, QB=128 (16 q-rows/wave), KVBLK=128,
// single-buffered, 2 barriers/tile, 16 tiles/block. LDS = 16K(K) + 16K(V) +
// 32K(P) = 64 KB -> exactly 2 blocks/CU; grid 512 = exactly 2/CU (no tail);
// 16 waves/CU. Each staged K/V byte serves 8 waves.
// Transposed dataflow (S^T / O^T): softmax reduction axis lane-local (q=ql).
// Q,K in [bh][L][64]; V in [bh][64][L]; O in [bh][L][64] (packed 8B stores).
// ---------------------------------------------------------------------------
__global__ __launch_bounds__(512, 4)
void attn_f16(const f16* __restrict__ Qh, const f16* __restrict__ Kh,
              const f16* __restrict__ VhT, f16* __restrict__ Ob)
{
    __shared__ __align__(16) char k_s[128 * 128];  // [key][kd] swz7, 16KB
    __shared__ __align__(16) char v_s[64 * 256];   // [kd][key] swz8, 16KB
    __shared__ __align__(16) char p_s[8 * 4096];   // per-wave P^T [q][key] swz8

    const int tid = threadIdx.x, lane = tid & 63, wid = tid >> 6;  // wid 0..7
    const int g = lane >> 4, ql = lane & 15;
    char* pw = p_s + wid * 4096;

    // XCD swizzle: 64 consecutive sb (4 bh) per XCD -> K/V L2-resident
    const int bid = blockIdx.x;                    // 0..511
    const int sb = (bid & 7) * 64 + (bid >> 3);
    const int qt = sb & 15, bh = sb >> 4;

    const f16*  Qb = Qh + (size_t)bh * LL * KDIM;
    const char* Kb = (const char*)(Kh + (size_t)bh * LL * KDIM);
    const char* Vb = (const char*)(VhT + (size_t)bh * KDIM * LL);
    const int q0 = qt * 128 + wid * 16;

    auto stage = [&](int t) {
        #pragma unroll
        for (int i = 0; i < 2; ++i) {
            const int xl = i * 8192 + wid * 1024 + lane * 16;
            gload16(Kb + (size_t)t * 16384 + swz7(xl), k_s + xl);
            const int xv = swz8(xl);
            gload16(Vb + (size_t)(xl >> 8) * (LL * 2) + t * 256 + (xv & 255),
                    v_s + xl);
        }
    };

    // Q fragments (B-operand: col=q, k=kd), scaled by 1/8 * log2(e)
    const f16 qscale = (f16)(0.125f * 1.44269504089f);
    f16x8 qfr[2];
    #pragma unroll
    for (int kb = 0; kb < 2; ++kb) {
        qfr[kb] = *(const f16x8*)(Qb + (size_t)(q0 + ql) * KDIM + kb * 32 + g * 8);
        qfr[kb] *= qscale;
    }

    const f32x4 zero = {0.f, 0.f, 0.f, 0.f};
    f32x4 acc[4];
    #pragma unroll
    for (int n = 0; n < 4; ++n) acc[n] = zero;
    float m_r = -1e30f, l_r = 0.f;

    for (int t = 0; t < 16; ++t) {
        stage(t);
        __syncthreads();                       // staging landed (vmcnt drain)

        // S^T = K Q^T : col = q (lane-local), rows = 128 keys
        f32x4 s[8];
        __builtin_amdgcn_s_setprio(1);
        #pragma unroll
        for (int kf = 0; kf < 8; ++kf) {
            f16x8 kfr0 = *(const f16x8*)(k_s + swz7((kf * 16 + ql) * 128 + g * 16));
            f16x8 kfr1 = *(const f16x8*)(k_s + swz7((kf * 16 + ql) * 128 + 64 + g * 16));
            f32x4 z = zero;
            z = __builtin_amdgcn_mfma_f32_16x16x32_f16(kfr0, qfr[0], z, 0, 0, 0);
            z = __builtin_amdgcn_mfma_f32_16x16x32_f16(kfr1, qfr[1], z, 0, 0, 0);
            s[kf] = z;
        }
        __builtin_amdgcn_s_setprio(0);

        // online softmax with defer-max (THR=8 in exp2 domain); balanced tree
        float t8[8];
        #pragma unroll
        for (int kf = 0; kf < 8; ++kf)
            t8[kf] = fmaxf(fmaxf(s[kf][0], s[kf][1]), fmaxf(s[kf][2], s[kf][3]));
        float mx = fmaxf(fmaxf(fmaxf(t8[0], t8[1]), fmaxf(t8[2], t8[3])),
                         fmaxf(fmaxf(t8[4], t8[5]), fmaxf(t8[6], t8[7])));
        mx = fmaxf(mx, __shfl_xor(mx, 16));
        mx = fmaxf(mx, __shfl_xor(mx, 32));
        if (__any(mx > m_r + 8.f)) {
            const float mnew = fmaxf(m_r, mx);
            const float fsc = exp2f(m_r - mnew);
            m_r = mnew;
            l_r *= fsc;
            #pragma unroll
            for (int n = 0; n < 4; ++n) acc[n] *= fsc;
        }
        float ps = 0.f;
        #pragma unroll
        for (int kf = 0; kf < 8; ++kf) {
            const float p0 = exp2f(s[kf][0] - m_r);
            const float p1 = exp2f(s[kf][1] - m_r);
            const float p2 = exp2f(s[kf][2] - m_r);
            const float p3 = exp2f(s[kf][3] - m_r);
            ps += (p0 + p1) + (p2 + p3);
            f16x4v pk = {(f16)p0, (f16)p1, (f16)p2, (f16)p3};
            *(f16x4v*)(pw + swz8(ql * 256 + kf * 32 + g * 8)) = pk;
        }
        l_r += ps;   // per-lane partial; cross-lane reduced once at epilogue

        // O^T += V^T P^T  (within-wave P produce->consume: lgkmcnt only)
        __builtin_amdgcn_s_setprio(1);
        #pragma unroll
        for (int kb = 0; kb < 4; ++kb) {
            f16x8 pf = *(const f16x8*)(pw + swz8(ql * 256 + kb * 64 + g * 16));
            #pragma unroll
            for (int n = 0; n < 4; ++n) {
                f16x8 vf = *(const f16x8*)(v_s + swz8((n * 16 + ql) * 256
                                                      + kb * 64 + g * 16));
                acc[n] = __builtin_amdgcn_mfma_f32_16x16x32_f16(vf, pf, acc[n], 0, 0, 0);
            }
        }
        __builtin_amdgcn_s_setprio(0);
        __syncthreads();                       // reads done -> safe to restage
    }

    // epilogue: reduce l across the 4 g-lanes (linear in all rescales), store
    l_r += __shfl_xor(l_r, 16);
    l_r += __shfl_xor(l_r, 32);
    const float inv = 1.f / l_r;
    const int q = q0 + ql;
    f16* orow = Ob + ((size_t)bh * LL + q) * KDIM;
    #pragma unroll
    for (int n = 0; n < 4; ++n) {
        f16x4v o = {(f16)(acc[n][0] * inv), (f16)(acc[n][1] * inv),
                    (f16)(acc[n][2] * inv), (f16)(acc[n][3] * inv)};
        *(f16x4v*)(orow + n * 16 + g * 4) = o;
    }
}

// ---------------------------------------------------------------------------
extern "C" void kernel_launch(void* const* d_in, const int* in_sizes, int n_in,
                              void* d_out, int out_size, void* d_ws, size_t ws_size,
                              hipStream_t stream)
{
    const float* query = (const float*)d_in[0];
    const float* key   = (const float*)d_in[1];
    const float* value = (const float*)d_in[2];
    const int* wq = (const int*)d_in[3];
    const int* wk = (const int*)d_in[4];
    const int* wv = (const int*)d_in[5];
    const int* wo = (const int*)d_in[6];
    const float* bq = (const float*)d_in[7];
    const float* bk = (const float*)d_in[8];
    const float* bv = (const float*)d_in[9];
    const float* bo = (const float*)d_in[10];
    const float* scale_q = (const float*)d_in[11];
    const float* scale_k = (const float*)d_in[12];
    const float* scale_v = (const float*)d_in[13];
    const float* scale_o = (const float*)d_in[14];
    const float* zp_q = (const float*)d_in[15];
    const float* zp_k = (const float*)d_in[16];
    const float* zp_v = (const float*)d_in[17];
    const float* zp_o = (const float*)d_in[18];

    const size_t MD = (size_t)BB * LL * DD;       // 4.19M
    const size_t WT_SZ = (size_t)DD * DD;

    f16* Xq  = (f16*)d_ws;
    f16* Xk  = Xq + MD;
    f16* Xv  = Xk + MD;
    f16* WTq = Xv + MD;
    f16* WTk = WTq + WT_SZ;
    f16* WTv = WTk + WT_SZ;
    f16* WTo = WTv + WT_SZ;
    f16* Qh  = WTo + WT_SZ;
    f16* Kh  = Qh + MD;
    f16* VhT = Kh + MD;
    f16* Ob  = VhT + MD;   // [b][h][q][64]

    prologue<<<1024 + 3 * 4096, 256, 0, stream>>>(
        wq, wk, wv, wo, scale_q, scale_k, scale_v, scale_o,
        zp_q, zp_k, zp_v, zp_o, WTq, WTk, WTv, WTo,
        query, key, value, Xq, Xk, Xv);

    dim3 gg(256, 1, 3);
    gemm_qkv<<<gg, 256, 0, stream>>>(Xq, Xk, Xv, WTq, WTk, WTv,
                                     bq, bk, bv, Qh, Kh, VhT);

    attn_f16<<<512, 512, 0, stream>>>(Qh, Kh, VhT, Ob);

    gemm_out<<<256, 256, 0, stream>>>(Ob, WTo, bo, (float*)d_out);
}

// Round 10
// 140.551 us; speedup vs baseline: 1.1170x; 1.0054x over previous
//
#include <hip/hip_runtime.h>
#include <math.h>
#include <stdint.h>

#define BB 4
#define LL 2048
#define DD 512
#define KDIM 64
#define HH 8

typedef _Float16 f16;
typedef f16 f16x8 __attribute__((ext_vector_type(8)));
typedef f16 f16x4v __attribute__((ext_vector_type(4)));
typedef float f32x4 __attribute__((ext_vector_type(4)));

// Involutive XOR swizzles: swz7 for 128B-row LDS tiles, swz8 for 256B rows.
__device__ __forceinline__ int swz7(int x) { return x ^ (((x >> 7) & 7) << 4); }
__device__ __forceinline__ int swz8(int x) { return x ^ (((x >> 8) & 7) << 4); }

__device__ __forceinline__ void gload16(const void* g, void* l) {
    __builtin_amdgcn_global_load_lds(
        (const __attribute__((address_space(1))) void*)g,
        (__attribute__((address_space(3))) void*)l, 16, 0, 0);
}

// Counted-drain barrier (GEMM pipeline): wait own staging loads, raw barrier.
__device__ __forceinline__ void wait_barrier() {
    asm volatile("s_waitcnt vmcnt(0)" ::: "memory");
    __builtin_amdgcn_s_barrier();
}

// ---------------------------------------------------------------------------
// Prologue: weight dequant+transpose (4 weights) AND fp32->fp16 casts (3
// activations) in ONE launch. 1D grid: bid<1024 -> prep, else cast.
// WO (zi==3): k-index permuted k' = (k&7)*64 + (k>>3) so the final GEMM can
// read the attention output in per-head [b][h][q][64] layout.
// ---------------------------------------------------------------------------
__global__ __launch_bounds__(256)
void prologue(const int* __restrict__ w0, const int* __restrict__ w1,
              const int* __restrict__ w2, const int* __restrict__ w3,
              const float* s0, const float* s1, const float* s2, const float* s3,
              const float* z0, const float* z1, const float* z2, const float* z3,
              f16* o0, f16* o1, f16* o2, f16* o3,
              const float* __restrict__ xq, const float* __restrict__ xk,
              const float* __restrict__ xv, f16* cq, f16* ck, f16* cv)
{
    __shared__ float t[32][33];
    const int bid = blockIdx.x;
    if (bid < 1024) {
        const int zi = bid >> 8, rem = bid & 255;
        const int* W = zi == 0 ? w0 : zi == 1 ? w1 : zi == 2 ? w2 : w3;
        const float sc = *(zi == 0 ? s0 : zi == 1 ? s1 : zi == 2 ? s2 : s3);
        const float zp = *(zi == 0 ? z0 : zi == 1 ? z1 : zi == 2 ? z2 : z3);
        f16* WT = zi == 0 ? o0 : zi == 1 ? o1 : zi == 2 ? o2 : o3;
        const int n0 = (rem & 15) * 32, k0 = (rem >> 4) * 32;
        const int x = threadIdx.x & 31, y = threadIdx.x >> 5;  // 32 x 8
        #pragma unroll
        for (int i = 0; i < 32; i += 8)
            t[y + i][x] = ((float)W[(size_t)(k0 + y + i) * DD + n0 + x] - zp) * sc;
        __syncthreads();
        if (zi == 3) {
            const int k = k0 + x;
            const int kp = (k & 7) * 64 + (k >> 3);
            #pragma unroll
            for (int i = 0; i < 32; i += 8)
                WT[(size_t)(n0 + y + i) * DD + kp] = (f16)t[x][y + i];
        } else {
            #pragma unroll
            for (int i = 0; i < 32; i += 8)
                WT[(size_t)(n0 + y + i) * DD + k0 + x] = (f16)t[x][y + i];
        }
    } else {
        const int c = bid - 1024;
        const int yi = c >> 12, xb = c & 4095;
        const float* in = yi == 0 ? xq : yi == 1 ? xk : xv;
        f16* out = yi == 0 ? cq : yi == 1 ? ck : cv;
        const int i = (xb * 256 + threadIdx.x) * 4;
        float4 v = *(const float4*)(in + i);
        f16x4v o = {(f16)v.x, (f16)v.y, (f16)v.z, (f16)v.w};
        *(f16x4v*)(out + i) = o;
    }
}

// ---------------------------------------------------------------------------
// MFMA GEMM body: Out[M=8192][N=512] = A[M][512] @ WT^T + bias.
// 128x128 tile, BK=32, 4 waves (2x2), 4x4 16x16x32 frags per wave.
// Double-buffered LDS, counted-vmcnt pipeline (one barrier per K-step).
// EPI=0: f16 per-head row-major [b*H+h][L][64]     (Q, K)
// EPI=1: fp32 [M][N]; A is per-head [b][h][q][64] with permuted-k weights
// EPI=2: f16 per-head col-major [b*H+h][64][L]     (V, pre-transposed)
// ---------------------------------------------------------------------------
template<int EPI>
__device__ __forceinline__
void gemm_body(char* As, char* Bs, const f16* __restrict__ A,
               const f16* __restrict__ BT, const float* __restrict__ bias,
               void* __restrict__ OutP)
{
    const int tid = threadIdx.x, lane = tid & 63, wid = tid >> 6;
    const int g = lane >> 4, ql = lane & 15;
    const int wm = wid >> 1, wn = wid & 1;
    const int bid = blockIdx.x;
    const int sb = (bid & 7) * 32 + (bid >> 3);    // XCD swizzle (256 blocks)
    const int rowBase = (sb >> 2) * 128, colBase = (sb & 3) * 128;

    auto stage = [&](int p, int buf) {
        const int kt = p * 32;
        #pragma unroll
        for (int i = 0; i < 2; ++i) {
            const int xl = i * 4096 + wid * 1024 + lane * 16;
            const int xs = swz7(xl);
            const int r = xs >> 6, cb = xs & 63;
            const char* asrc;
            if (EPI == 1) {
                const int m = rowBase + r, b = m >> 11, qq = m & 2047;
                const int kp = kt * 2 + cb;
                asrc = (const char*)A +
                       (((size_t)((b * 8 + (kp >> 7)) * 2048 + qq)) << 7) + (kp & 127);
            } else {
                asrc = (const char*)(A + (size_t)(rowBase + r) * DD + kt) + cb;
            }
            gload16(asrc, As + buf * 8192 + xl);
            gload16((const char*)(BT + (size_t)(colBase + r) * DD + kt) + cb,
                    Bs + buf * 8192 + xl);
        }
    };

    const f32x4 zero = {0.f, 0.f, 0.f, 0.f};
    f32x4 acc[4][4];
    #pragma unroll
    for (int i = 0; i < 4; ++i)
        #pragma unroll
        for (int j = 0; j < 4; ++j) acc[i][j] = zero;

    stage(0, 0);

    for (int p = 0; p < 16; ++p) {
        const int buf = p & 1;
        wait_barrier();                 // own stage(p) landed; all waves synced
        if (p < 15) stage(p + 1, buf ^ 1);   // stays in flight across next barrier
        const char* as = As + buf * 8192;
        const char* bs = Bs + buf * 8192;
        f16x8 af[4], bf[4];
        #pragma unroll
        for (int mf = 0; mf < 4; ++mf)
            af[mf] = *(const f16x8*)(as + swz7((wm * 64 + mf * 16 + ql) * 64 + g * 16));
        #pragma unroll
        for (int nf = 0; nf < 4; ++nf)
            bf[nf] = *(const f16x8*)(bs + swz7((wn * 64 + nf * 16 + ql) * 64 + g * 16));
        __builtin_amdgcn_s_setprio(1);
        #pragma unroll
        for (int mf = 0; mf < 4; ++mf)
            #pragma unroll
            for (int nf = 0; nf < 4; ++nf)
                acc[mf][nf] = __builtin_amdgcn_mfma_f32_16x16x32_f16(af[mf], bf[nf], acc[mf][nf], 0, 0, 0);
        __builtin_amdgcn_s_setprio(0);
    }

    #pragma unroll
    for (int nf = 0; nf < 4; ++nf) {
        const int n = colBase + wn * 64 + nf * 16 + ql;
        const float bn = bias[n];
        #pragma unroll
        for (int mf = 0; mf < 4; ++mf) {
            const int m0 = rowBase + wm * 64 + mf * 16 + g * 4;
            if (EPI == 2) {
                const int b = m0 >> 11, l0 = m0 & 2047;
                const int kd = n >> 3, hh = n & 7;
                f16x4v o = {(f16)(acc[mf][nf][0] + bn), (f16)(acc[mf][nf][1] + bn),
                            (f16)(acc[mf][nf][2] + bn), (f16)(acc[mf][nf][3] + bn)};
                *(f16x4v*)((f16*)OutP + ((size_t)(b * HH + hh) * KDIM + kd) * LL + l0) = o;
            } else {
                #pragma unroll
                for (int r = 0; r < 4; ++r) {
                    const int m = m0 + r;
                    const float v = acc[mf][nf][r] + bn;
                    if (EPI == 0) {
                        const int b = m >> 11, lr = m & 2047;
                        const int kd = n >> 3, hh = n & 7;
                        ((f16*)OutP)[((size_t)(b * HH + hh) * LL + lr) * KDIM + kd] = (f16)v;
                    } else {
                        ((float*)OutP)[(size_t)m * DD + n] = v;
                    }
                }
            }
        }
    }
}

__global__ __launch_bounds__(256)
void gemm_qkv(const f16* Xq, const f16* Xk, const f16* Xv,
              const f16* WTq, const f16* WTk, const f16* WTv,
              const float* bq, const float* bk, const float* bv,
              f16* Qh, f16* Kh, f16* VhT)
{
    __shared__ __align__(16) char As[2 * 128 * 32 * 2];
    __shared__ __align__(16) char Bs[2 * 128 * 32 * 2];
    const int z = blockIdx.z;
    if (z == 0)      gemm_body<0>(As, Bs, Xq, WTq, bq, Qh);
    else if (z == 1) gemm_body<0>(As, Bs, Xk, WTk, bk, Kh);
    else             gemm_body<2>(As, Bs, Xv, WTv, bv, VhT);
}

__global__ __launch_bounds__(256)
void gemm_out(const f16* A, const f16* BT, const float* bias, float* Out)
{
    __shared__ __align__(16) char As[2 * 128 * 32 * 2];
    __shared__ __align__(16) char Bs[2 * 128 * 32 * 2];
    gemm_body<1>(As, Bs, A, BT, bias, Out);
}

// ---------------------------------------------------------------------------
// MFMA flash attention. 8-wave blocks, QB=128 (16 q-rows/wave), KVBLK=128,
// 16 tiles/block, grid 512 = 2 blocks/CU, LDS 64 KB (K 16K + V 16K + P 32K).
// Pipeline per tile (2 raw barriers, all drains covered):
//   [ds_write K(t) regs; lgkmcnt(0); barrier]  <- K published, PV(t-1) closed
//   [issue V(t) gload_lds + K(t+1)->regs]      <- in flight under QK^T+softmax
//   [QK^T; softmax; P writes]
//   [vmcnt(0); barrier]                        <- V published (fully covered)
//   [PV]
// All LDS frag addresses precomputed per-lane (XOR part is lane-constant),
// loop offsets are compile-time (kf*2048 / n*4096) -> fold into ds offsets.
// Transposed dataflow (S^T / O^T): softmax reduction axis lane-local (q=ql).
// Q,K in [bh][L][64]; V in [bh][64][L]; O in [bh][L][64] (packed 8B stores).
// ---------------------------------------------------------------------------
__global__ __launch_bounds__(512, 4)
void attn_f16(const f16* __restrict__ Qh, const f16* __restrict__ Kh,
              const f16* __restrict__ VhT, f16* __restrict__ Ob)
{
    __shared__ __align__(16) char k_s[128 * 128];  // [key][kd] swz7, 16KB
    __shared__ __align__(16) char v_s[64 * 256];   // [kd][key] swz8, 16KB
    __shared__ __align__(16) char p_s[8 * 4096];   // per-wave P^T [q][key] swz8

    const int tid = threadIdx.x, lane = tid & 63, wid = tid >> 6;  // wid 0..7
    const int g = lane >> 4, ql = lane & 15;

    // XCD swizzle: 64 consecutive sb (4 bh) per XCD -> K/V L2-resident
    const int bid = blockIdx.x;                    // 0..511
    const int sb = (bid & 7) * 64 + (bid >> 3);
    const int qt = sb & 15, bh = sb >> 4;

    const f16*  Qb = Qh + (size_t)bh * LL * KDIM;
    const char* Kb = (const char*)(Kh + (size_t)bh * LL * KDIM);
    const char* Vb = (const char*)(VhT + (size_t)bh * KDIM * LL);
    const int q0 = qt * 128 + wid * 16;

    // ---- precomputed per-lane addresses (loop offsets are literals) ----
    const int xl0 = wid * 1024 + lane * 16;
    const int xl1 = 8192 + wid * 1024 + lane * 16;
    const char* ks0 = Kb + swz7(xl0);                        // + t*16384
    const char* ks1 = Kb + swz7(xl1);
    const char* vs0 = Vb + (xl0 >> 8) * (LL * 2) + (swz8(xl0) & 255);  // + t*256
    const char* vs1 = Vb + (xl1 >> 8) * (LL * 2) + (swz8(xl1) & 255);
    char* kd0 = k_s + xl0;  char* kd1 = k_s + xl1;           // linear dests
    char* vd0 = v_s + xl0;  char* vd1 = v_s + xl1;

    const char* kb0 = k_s + swz7(ql * 128 + g * 16);         // + kf*2048
    const char* kb1 = k_s + swz7(ql * 128 + 64 + g * 16);    // + kf*2048
    char* pw = p_s + wid * 4096;
    const char* vbs[4]; const char* prs[4]; char* pwa[8];
    #pragma unroll
    for (int kb = 0; kb < 4; ++kb) {
        vbs[kb] = v_s + swz8(ql * 256 + kb * 64 + g * 16);   // + n*4096
        prs[kb] = pw  + swz8(ql * 256 + kb * 64 + g * 16);
    }
    #pragma unroll
    for (int kf = 0; kf < 8; ++kf)
        pwa[kf] = pw + swz8(ql * 256 + kf * 32 + g * 8);

    // Q fragments (B-operand: col=q, k=kd), scaled by 1/8 * log2(e)
    const f16 qscale = (f16)(0.125f * 1.44269504089f);
    f16x8 qfr[2];
    #pragma unroll
    for (int kb = 0; kb < 2; ++kb) {
        qfr[kb] = *(const f16x8*)(Qb + (size_t)(q0 + ql) * KDIM + kb * 32 + g * 8);
        qfr[kb] *= qscale;
    }

    const f32x4 zero = {0.f, 0.f, 0.f, 0.f};
    f32x4 acc[4];
    #pragma unroll
    for (int n = 0; n < 4; ++n) acc[n] = zero;
    float m_r = -1e30f, l_r = 0.f;

    // prologue: K(0) -> registers
    f16x8 kreg0 = *(const f16x8*)ks0;
    f16x8 kreg1 = *(const f16x8*)ks1;

    for (int t = 0; t < 16; ++t) {
        // publish K(t): regs -> LDS (k_s reads of t-1 all done pre-barrier-2)
        *(f16x8*)kd0 = kreg0;
        *(f16x8*)kd1 = kreg1;
        asm volatile("s_waitcnt lgkmcnt(0)" ::: "memory");
        __builtin_amdgcn_s_barrier();              // K(t) visible; v_s free

        // stage V(t) (direct-to-LDS) + prefetch K(t+1) into registers
        gload16(vs0 + t * 256, vd0);
        gload16(vs1 + t * 256, vd1);
        const int tn = (t + 1) & 15;               // t=15: harmless reload
        kreg0 = *(const f16x8*)(ks0 + tn * 16384);
        kreg1 = *(const f16x8*)(ks1 + tn * 16384);

        // S^T = K Q^T : col = q (lane-local), rows = 128 keys
        f32x4 s[8];
        __builtin_amdgcn_s_setprio(1);
        #pragma unroll
        for (int kf = 0; kf < 8; ++kf) {
            f16x8 kfr0 = *(const f16x8*)(kb0 + kf * 2048);
            f16x8 kfr1 = *(const f16x8*)(kb1 + kf * 2048);
            f32x4 z = zero;
            z = __builtin_amdgcn_mfma_f32_16x16x32_f16(kfr0, qfr[0], z, 0, 0, 0);
            z = __builtin_amdgcn_mfma_f32_16x16x32_f16(kfr1, qfr[1], z, 0, 0, 0);
            s[kf] = z;
        }
        __builtin_amdgcn_s_setprio(0);

        // online softmax with defer-max (THR=8 in exp2 domain); balanced tree
        float t8[8];
        #pragma unroll
        for (int kf = 0; kf < 8; ++kf)
            t8[kf] = fmaxf(fmaxf(s[kf][0], s[kf][1]), fmaxf(s[kf][2], s[kf][3]));
        float mx = fmaxf(fmaxf(fmaxf(t8[0], t8[1]), fmaxf(t8[2], t8[3])),
                         fmaxf(fmaxf(t8[4], t8[5]), fmaxf(t8[6], t8[7])));
        mx = fmaxf(mx, __shfl_xor(mx, 16));
        mx = fmaxf(mx, __shfl_xor(mx, 32));
        if (__any(mx > m_r + 8.f)) {
            const float mnew = fmaxf(m_r, mx);
            const float fsc = exp2f(m_r - mnew);
            m_r = mnew;
            l_r *= fsc;
            #pragma unroll
            for (int n = 0; n < 4; ++n) acc[n] *= fsc;
        }
        float ps = 0.f;
        #pragma unroll
        for (int kf = 0; kf < 8; ++kf) {
            const float p0 = exp2f(s[kf][0] - m_r);
            const float p1 = exp2f(s[kf][1] - m_r);
            const float p2 = exp2f(s[kf][2] - m_r);
            const float p3 = exp2f(s[kf][3] - m_r);
            ps += (p0 + p1) + (p2 + p3);
            f16x4v pk = {(f16)p0, (f16)p1, (f16)p2, (f16)p3};
            *(f16x4v*)pwa[kf] = pk;
        }
        l_r += ps;   // per-lane partial; cross-lane reduced once at epilogue

        // V(t) published (drain covered by QK^T+softmax above)
        asm volatile("s_waitcnt vmcnt(0)" ::: "memory");
        __builtin_amdgcn_s_barrier();

        // O^T += V^T P^T
        __builtin_amdgcn_s_setprio(1);
        #pragma unroll
        for (int kb = 0; kb < 4; ++kb) {
            f16x8 pf = *(const f16x8*)prs[kb];
            #pragma unroll
            for (int n = 0; n < 4; ++n) {
                f16x8 vf = *(const f16x8*)(vbs[kb] + n * 4096);
                acc[n] = __builtin_amdgcn_mfma_f32_16x16x32_f16(vf, pf, acc[n], 0, 0, 0);
            }
        }
        __builtin_amdgcn_s_setprio(0);
    }

    // epilogue: reduce l across the 4 g-lanes (linear in all rescales), store
    l_r += __shfl_xor(l_r, 16);
    l_r += __shfl_xor(l_r, 32);
    const float inv = 1.f / l_r;
    const int q = q0 + ql;
    f16* orow = Ob + ((size_t)bh * LL + q) * KDIM;
    #pragma unroll
    for (int n = 0; n < 4; ++n) {
        f16x4v o = {(f16)(acc[n][0] * inv), (f16)(acc[n][1] * inv),
                    (f16)(acc[n][2] * inv), (f16)(acc[n][3] * inv)};
        *(f16x4v*)(orow + n * 16 + g * 4) = o;
    }
}

// ---------------------------------------------------------------------------
extern "C" void kernel_launch(void* const* d_in, const int* in_sizes, int n_in,
                              void* d_out, int out_size, void* d_ws, size_t ws_size,
                              hipStream_t stream)
{
    const float* query = (const float*)d_in[0];
    const float* key   = (const float*)d_in[1];
    const float* value = (const float*)d_in[2];
    const int* wq = (const int*)d_in[3];
    const int* wk = (const int*)d_in[4];
    const int* wv = (const int*)d_in[5];
    const int* wo = (const int*)d_in[6];
    const float* bq = (const float*)d_in[7];
    const float* bk = (const float*)d_in[8];
    const float* bv = (const float*)d_in[9];
    const float* bo = (const float*)d_in[10];
    const float* scale_q = (const float*)d_in[11];
    const float* scale_k = (const float*)d_in[12];
    const float* scale_v = (const float*)d_in[13];
    const float* scale_o = (const float*)d_in[14];
    const float* zp_q = (const float*)d_in[15];
    const float* zp_k = (const float*)d_in[16];
    const float* zp_v = (const float*)d_in[17];
    const float* zp_o = (const float*)d_in[18];

    const size_t MD = (size_t)BB * LL * DD;       // 4.19M
    const size_t WT_SZ = (size_t)DD * DD;

    f16* Xq  = (f16*)d_ws;
    f16* Xk  = Xq + MD;
    f16* Xv  = Xk + MD;
    f16* WTq = Xv + MD;
    f16* WTk = WTq + WT_SZ;
    f16* WTv = WTk + WT_SZ;
    f16* WTo = WTv + WT_SZ;
    f16* Qh  = WTo + WT_SZ;
    f16* Kh  = Qh + MD;
    f16* VhT = Kh + MD;
    f16* Ob  = VhT + MD;   // [b][h][q][64]

    prologue<<<1024 + 3 * 4096, 256, 0, stream>>>(
        wq, wk, wv, wo, scale_q, scale_k, scale_v, scale_o,
        zp_q, zp_k, zp_v, zp_o, WTq, WTk, WTv, WTo,
        query, key, value, Xq, Xk, Xv);

    dim3 gg(256, 1, 3);
    gemm_qkv<<<gg, 256, 0, stream>>>(Xq, Xk, Xv, WTq, WTk, WTv,
                                     bq, bk, bv, Qh, Kh, VhT);

    attn_f16<<<512, 512, 0, stream>>>(Qh, Kh, VhT, Ob);

    gemm_out<<<256, 256, 0, stream>>>(Ob, WTo, bo, (float*)d_out);
}